// Round 1
// baseline (10475.352 us; speedup 1.0000x reference)
//
#include <hip/hip_runtime.h>
#include <hip/hip_bf16.h>
#include <math.h>

#define B_   2
#define S_   2048
#define D_   512
#define H_   8
#define DH_  64
#define L_   6
#define DFF_ 2048
#define BS_  (B_*S_)        // 4096 rows
#define BSD_ (B_*S_*D_)     // 2097152 elems

// ---------------- embedding: h = word_e[x] + pos_e ----------------
__global__ __launch_bounds__(256) void embed_kernel(
    const int* __restrict__ x, const float* __restrict__ we,
    const float* __restrict__ pe, float* __restrict__ h) {
  int idx = blockIdx.x * 256 + threadIdx.x;   // over B*S*D
  int d  = idx & (D_ - 1);
  int bs = idx >> 9;                          // / 512
  int s  = bs & (S_ - 1);
  h[idx] = we[(size_t)x[bs] * D_ + d] + pe[(size_t)s * D_ + d];
}

// ---------------- fp32 tiled GEMM: C[M,N] = A[M,K] @ W[K,N] (+bias, relu) ----
// tile 64x64, K-tile 32, 256 threads, 4x4 outputs/thread. M = gridDim.y*64.
__global__ __launch_bounds__(256) void gemm_f32(
    const float* __restrict__ A, const float* __restrict__ W,
    const float* __restrict__ bias, float* __restrict__ C,
    int N, int K, int do_relu) {
  __shared__ float As[64][33];
  __shared__ float Ws[32][65];
  const int tid = threadIdx.x;
  const int tr = tid >> 4, tc = tid & 15;
  const int row0 = blockIdx.y * 64;
  const int col0 = blockIdx.x * 64;
  float acc[4][4] = {};
  for (int k0 = 0; k0 < K; k0 += 32) {
    #pragma unroll
    for (int i = tid; i < 64 * 32; i += 256) {
      int r = i >> 5, c = i & 31;
      As[r][c] = A[(size_t)(row0 + r) * K + k0 + c];
    }
    #pragma unroll
    for (int i = tid; i < 32 * 64; i += 256) {
      int r = i >> 6, c = i & 63;
      Ws[r][c] = W[(size_t)(k0 + r) * N + col0 + c];
    }
    __syncthreads();
    #pragma unroll
    for (int kk = 0; kk < 32; ++kk) {
      float a[4], w[4];
      #pragma unroll
      for (int m = 0; m < 4; ++m) a[m] = As[tr * 4 + m][kk];
      #pragma unroll
      for (int n = 0; n < 4; ++n) w[n] = Ws[kk][tc * 4 + n];
      #pragma unroll
      for (int m = 0; m < 4; ++m)
        #pragma unroll
        for (int n = 0; n < 4; ++n)
          acc[m][n] = fmaf(a[m], w[n], acc[m][n]);
    }
    __syncthreads();
  }
  #pragma unroll
  for (int m = 0; m < 4; ++m) {
    int row = row0 + tr * 4 + m;
    #pragma unroll
    for (int n = 0; n < 4; ++n) {
      int col = col0 + tc * 4 + n;
      float vv = acc[m][n];
      if (bias) vv += bias[col];
      if (do_relu) vv = fmaxf(vv, 0.f);
      C[(size_t)row * N + col] = vv;
    }
  }
}

// ---------------- fused attention (online softmax, flash-style) -------------
// One block = (b, head, 32 query rows). 256 threads: row r = tid>>3 (32 rows),
// sub = tid&7 handles 8 j's (scores) and 8 d's (PV accumulation).
__global__ __launch_bounds__(256) void attn_kernel(
    const float* __restrict__ q, const float* __restrict__ k,
    const float* __restrict__ v, const int* __restrict__ mask,
    float* __restrict__ ctx) {
  const int nit = S_ / 32;                 // 64 i-tiles
  int bid = blockIdx.x;
  int it = bid % nit;
  int hh = (bid / nit) % H_;
  int b  = bid / (nit * H_);

  __shared__ float q_s[32][65];
  __shared__ float k_s[64][65];
  __shared__ float v_s[64][65];
  __shared__ float p_s[32][65];
  __shared__ int   m_s[64];

  const int tid = threadIdx.x;
  const int r   = tid >> 3;    // query row in tile, 0..31
  const int sub = tid & 7;     // 0..7
  const int d0  = sub * 8;

  for (int i = tid; i < 32 * 64; i += 256) {
    int rl = i >> 6, d = i & 63;
    q_s[rl][d] = q[(size_t)(b * S_ + it * 32 + rl) * D_ + hh * DH_ + d];
  }

  float mrow = -1e30f, lsum = 0.f;
  float acc[8];
  #pragma unroll
  for (int i = 0; i < 8; ++i) acc[i] = 0.f;

  const float inv_scale = 0.044194173824159216f;   // 1/sqrt(D=512), per reference

  for (int j0 = 0; j0 < S_; j0 += 64) {
    __syncthreads();   // previous iteration done reading k_s/v_s/p_s
    for (int i = tid; i < 64 * 64; i += 256) {
      int jr = i >> 6, d = i & 63;
      size_t base = (size_t)(b * S_ + j0 + jr) * D_ + hh * DH_ + d;
      k_s[jr][d] = k[base];
      v_s[jr][d] = v[base];
    }
    if (tid < 64) m_s[tid] = mask[b * S_ + j0 + tid];
    __syncthreads();

    // scores for this thread's 8 j's
    float sc[8];
    #pragma unroll
    for (int jj = 0; jj < 8; ++jj) {
      int jl = sub * 8 + jj;
      float dot = 0.f;
      #pragma unroll
      for (int d = 0; d < 64; ++d) dot = fmaf(q_s[r][d], k_s[jl][d], dot);
      dot *= inv_scale;
      if (m_s[jl] == 0) dot = -1e20f;
      sc[jj] = dot;
    }
    float cmax = sc[0];
    #pragma unroll
    for (int jj = 1; jj < 8; ++jj) cmax = fmaxf(cmax, sc[jj]);
    #pragma unroll
    for (int o = 1; o < 8; o <<= 1) cmax = fmaxf(cmax, __shfl_xor(cmax, o));

    float mnew = fmaxf(mrow, cmax);
    float corr = __expf(mrow - mnew);
    lsum *= corr;
    #pragma unroll
    for (int i = 0; i < 8; ++i) acc[i] *= corr;

    float psum = 0.f;
    #pragma unroll
    for (int jj = 0; jj < 8; ++jj) {
      float p = __expf(sc[jj] - mnew);
      psum += p;
      p_s[r][sub * 8 + jj] = p;
    }
    #pragma unroll
    for (int o = 1; o < 8; o <<= 1) psum += __shfl_xor(psum, o);
    lsum += psum;
    mrow = mnew;
    __syncthreads();   // p_s visible to the whole row group

    #pragma unroll 8
    for (int j = 0; j < 64; ++j) {
      float p = p_s[r][j];
      #pragma unroll
      for (int dd = 0; dd < 8; ++dd)
        acc[dd] = fmaf(p, v_s[j][d0 + dd], acc[dd]);
    }
  }

  float inv = 1.f / lsum;
  size_t o = (size_t)(b * S_ + it * 32 + r) * D_ + hh * DH_ + d0;
  #pragma unroll
  for (int dd = 0; dd < 8; ++dd) ctx[o + dd] = acc[dd] * inv;
}

// ---------------- add + LayerNorm: out = LN(a + b) * g + be ------------------
// one block per row, 256 threads, D=512 -> 2 elems/thread. out may alias b.
__global__ __launch_bounds__(256) void ln_add_kernel(
    const float* __restrict__ a, const float* __restrict__ bsrc,
    const float* __restrict__ g, const float* __restrict__ be,
    float* __restrict__ out) {
  int row = blockIdx.x;
  int tid = threadIdx.x;
  size_t base = (size_t)row * D_;
  float s0 = a[base + tid]       + bsrc[base + tid];
  float s1 = a[base + 256 + tid] + bsrc[base + 256 + tid];
  float sum = s0 + s1;
  #pragma unroll
  for (int o = 1; o < 64; o <<= 1) sum += __shfl_xor(sum, o);
  __shared__ float red[4], red2[4];
  int w = tid >> 6, lane = tid & 63;
  if (lane == 0) red[w] = sum;
  __syncthreads();
  float mu = (red[0] + red[1] + red[2] + red[3]) * (1.f / D_);
  float d0 = s0 - mu, d1 = s1 - mu;
  float vs = d0 * d0 + d1 * d1;
  #pragma unroll
  for (int o = 1; o < 64; o <<= 1) vs += __shfl_xor(vs, o);
  if (lane == 0) red2[w] = vs;
  __syncthreads();
  float var = (red2[0] + red2[1] + red2[2] + red2[3]) * (1.f / D_);
  float rstd = rsqrtf(var + 1e-5f);
  out[base + tid]       = d0 * rstd * g[tid]       + be[tid];
  out[base + 256 + tid] = d1 * rstd * g[256 + tid] + be[256 + tid];
}

extern "C" void kernel_launch(void* const* d_in, const int* in_sizes, int n_in,
                              void* d_out, int out_size, void* d_ws, size_t ws_size,
                              hipStream_t stream) {
  (void)in_sizes; (void)n_in; (void)out_size; (void)ws_size;
  const int*   x      = (const int*)  d_in[0];
  const int*   mask   = (const int*)  d_in[1];
  const float* word_e = (const float*)d_in[2];
  const float* pos_e  = (const float*)d_in[3];
  const float* Wv     = (const float*)d_in[4];
  const float* Wk     = (const float*)d_in[5];
  const float* Wq     = (const float*)d_in[6];
  const float* Wo     = (const float*)d_in[7];
  const float* bo     = (const float*)d_in[8];
  const float* W1     = (const float*)d_in[9];
  const float* b1     = (const float*)d_in[10];
  const float* W2     = (const float*)d_in[11];
  const float* b2     = (const float*)d_in[12];
  const float* gamma  = (const float*)d_in[13];
  const float* beta   = (const float*)d_in[14];
  float* out = (float*)d_out;

  // workspace layout (floats): h | h1 | bufA(4*BSD_)
  //   bufA holds q,k,v,ctx during attention; ff1 (B*S*DFF = 4*BSD_) overlays it.
  float* ws  = (float*)d_ws;
  float* h    = ws;
  float* h1   = h + BSD_;
  float* bufA = h1 + BSD_;
  float* qb  = bufA;
  float* kb  = bufA + (size_t)BSD_;
  float* vb  = bufA + (size_t)2 * BSD_;
  float* ctx = bufA + (size_t)3 * BSD_;
  float* ff1 = bufA;                       // 4*BSD_ floats

  dim3 blk(256);
  embed_kernel<<<BSD_ / 256, blk, 0, stream>>>(x, word_e, pos_e, h);

  for (int l = 0; l < L_; ++l) {
    const float* Wq_l = Wq + (size_t)l * D_ * D_;
    const float* Wk_l = Wk + (size_t)l * D_ * D_;
    const float* Wv_l = Wv + (size_t)l * D_ * D_;
    const float* Wo_l = Wo + (size_t)l * D_ * D_;
    const float* bo_l = bo + (size_t)l * D_;
    const float* W1_l = W1 + (size_t)l * D_ * DFF_;
    const float* b1_l = b1 + (size_t)l * DFF_;
    const float* W2_l = W2 + (size_t)l * DFF_ * D_;
    const float* b2_l = b2 + (size_t)l * D_;
    const float* g_l  = gamma + (size_t)l * D_;
    const float* be_l = beta  + (size_t)l * D_;

    dim3 gD(D_ / 64, BS_ / 64);      // N=512 tiles
    dim3 gF(DFF_ / 64, BS_ / 64);    // N=2048 tiles

    gemm_f32<<<gD, blk, 0, stream>>>(h, Wq_l, nullptr, qb, D_, D_, 0);
    gemm_f32<<<gD, blk, 0, stream>>>(h, Wk_l, nullptr, kb, D_, D_, 0);
    gemm_f32<<<gD, blk, 0, stream>>>(h, Wv_l, nullptr, vb, D_, D_, 0);

    attn_kernel<<<B_ * H_ * (S_ / 32), blk, 0, stream>>>(qb, kb, vb, mask, ctx);

    gemm_f32<<<gD, blk, 0, stream>>>(ctx, Wo_l, bo_l, qb, D_, D_, 0);   // attn_out -> qb
    ln_add_kernel<<<BS_, blk, 0, stream>>>(qb, h, g_l, be_l, h1);

    gemm_f32<<<gF, blk, 0, stream>>>(h1, W1_l, b1_l, ff1, DFF_, D_, 1); // relu
    gemm_f32<<<gD, blk, 0, stream>>>(ff1, W2_l, b2_l, h, D_, DFF_, 0);  // ff2 -> h (h dead)
    ln_add_kernel<<<BS_, blk, 0, stream>>>(h1, h, g_l, be_l, (l == L_ - 1) ? out : h);
  }
}

// Round 5
// 1168.923 us; speedup vs baseline: 8.9615x; 8.9615x over previous
//
#include <hip/hip_runtime.h>
#include <hip/hip_bf16.h>
#include <math.h>

#define B_   2
#define S_   2048
#define D_   512
#define H_   8
#define L_   6
#define DFF_ 2048
#define BS_  (B_*S_)
#define BSD_ ((size_t)BS_*D_)
#define DD_  ((size_t)D_*D_)
#define DF_  ((size_t)D_*DFF_)

typedef __attribute__((ext_vector_type(8))) short bf16x8;
typedef __attribute__((ext_vector_type(4))) float f32x4;
typedef __attribute__((ext_vector_type(2))) unsigned int u32x2;
typedef __attribute__((ext_vector_type(4))) unsigned int u32x4;

#define MFMA_B16(A,Bv,C) __builtin_amdgcn_mfma_f32_16x16x32_bf16(A,Bv,C,0,0,0)

__device__ __forceinline__ void gload16(const void* g, void* l) {
  __builtin_amdgcn_global_load_lds(
      (const __attribute__((address_space(1))) unsigned int*)g,
      (__attribute__((address_space(3))) unsigned int*)l, 16, 0, 0);
}
__device__ __forceinline__ short f2bf(float x) {
  __hip_bfloat16 h = __float2bfloat16(x);
  return __builtin_bit_cast(short, h);
}

// ---- combined per-layer weight transpose+cvt: wt = [Wq^T|Wk^T|Wv^T|Wo^T|W1^T|W2^T]
// 3072 tiles of 32x32. Wt[n][k] = bf16(W[k][n]).
__global__ __launch_bounds__(256) void wtrans_layer(
    const float* Wq, const float* Wk, const float* Wv, const float* Wo,
    const float* W1, const float* W2, __hip_bfloat16* wt) {
  __shared__ float ts[32][33];
  int tt = blockIdx.x;
  const float* src;
  size_t dof;
  int K, N, kt, nt;
  if (tt < 1024) {
    int m = tt >> 8, loc = tt & 255;
    src = (m == 0) ? Wq : (m == 1) ? Wk : (m == 2) ? Wv : Wo;
    dof = (size_t)m * DD_; K = D_; N = D_; nt = loc & 15; kt = loc >> 4;
  } else if (tt < 2048) {
    int loc = tt - 1024;
    src = W1; dof = 4 * DD_; K = D_; N = DFF_; nt = loc & 63; kt = loc >> 6;
  } else {
    int loc = tt - 2048;
    src = W2; dof = 4 * DD_ + DF_; K = DFF_; N = D_; nt = loc & 15; kt = loc >> 4;
  }
  int n0 = nt * 32, k0 = kt * 32;
  int tc = threadIdx.x & 31, tg = threadIdx.x >> 5;
  #pragma unroll
  for (int i = 0; i < 4; ++i) {
    int r = tg + i * 8;
    ts[r][tc] = src[(size_t)(k0 + r) * N + n0 + tc];
  }
  __syncthreads();
  #pragma unroll
  for (int i = 0; i < 4; ++i) {
    int r = tg + i * 8;
    wt[dof + (size_t)(n0 + r) * K + k0 + tc] = __float2bfloat16(ts[tc][r]);
  }
}

// ---- V transpose per batch: vT[b][d][j] = v[b][j][d] (bf16) ----
__global__ __launch_bounds__(256) void vtrans(
    const __hip_bfloat16* v, __hip_bfloat16* vT) {
  __shared__ __hip_bfloat16 ts[32][33];
  int b = blockIdx.z;
  int j0 = blockIdx.x * 32, d0 = blockIdx.y * 32;
  int tc = threadIdx.x & 31, tg = threadIdx.x >> 5;
  #pragma unroll
  for (int i = 0; i < 4; ++i) {
    int r = tg + i * 8;
    ts[r][tc] = v[((size_t)b * S_ + j0 + r) * D_ + d0 + tc];
  }
  __syncthreads();
  #pragma unroll
  for (int i = 0; i < 4; ++i) {
    int r = tg + i * 8;
    vT[((size_t)b * D_ + d0 + r) * S_ + j0 + tc] = ts[tc][r];
  }
}

// ---- maskadd: -1e20 where mask==0 ----
__global__ __launch_bounds__(256) void maskadd_kernel(
    const int* __restrict__ mask, float* __restrict__ ma) {
  int i = blockIdx.x * 256 + threadIdx.x;
  ma[i] = (mask[i] == 0) ? -1e20f : 0.f;
}

// ---- embedding ----
__global__ __launch_bounds__(256) void embed_kernel(
    const int* __restrict__ x, const float* __restrict__ we,
    const float* __restrict__ pe, float* __restrict__ h,
    __hip_bfloat16* __restrict__ hbf) {
  int idx = blockIdx.x * 256 + threadIdx.x;
  int d = idx & (D_ - 1);
  int bs = idx >> 9;
  int s = bs & (S_ - 1);
  float vv = we[(size_t)x[bs] * D_ + d] + pe[(size_t)s * D_ + d];
  h[idx] = vv;
  hbf[idx] = __float2bfloat16(vv);
}

// ---- bf16 MFMA GEMM: C[M,N] = A[M,K] @ Bt[N,K]^T (+bias,relu) ----
// tile 64(M) x 128(N), BK=64, 256 threads = 4 waves 2x2 (wave tile 32x64).
template<int OUT_BF16, int RELU>
__global__ __launch_bounds__(256) void gemm_bf16(
    const __hip_bfloat16* __restrict__ A, const __hip_bfloat16* __restrict__ Bt,
    const float* __restrict__ bias, void* __restrict__ Cout,
    int N, int K, size_t zsB, size_t zsC) {
  __shared__ __hip_bfloat16 a_s[64 * 64];
  __shared__ __hip_bfloat16 b_s[128 * 64];
  const int tid = threadIdx.x;
  const int l = tid & 63, w = tid >> 6;
  const int lr = l & 15, lg = l >> 4;
  const int wr = w >> 1, wc = w & 1;
  const int row0 = blockIdx.y * 64, col0 = blockIdx.x * 128;
  Bt += (size_t)blockIdx.z * zsB;
  f32x4 acc[2][4];
  #pragma unroll
  for (int i = 0; i < 2; ++i)
    #pragma unroll
    for (int j = 0; j < 4; ++j) acc[i][j] = (f32x4){0.f, 0.f, 0.f, 0.f};

  for (int k0 = 0; k0 < K; k0 += 64) {
    __syncthreads();
    #pragma unroll
    for (int i = 0; i < 2; ++i) {        // A tile: 64 rows x 64 k
      int t = i * 256 + tid;
      int r = t >> 3, c = (t & 7) ^ (r & 7);
      gload16(A + (size_t)(row0 + r) * K + k0 + c * 8, (char*)a_s + t * 16);
    }
    #pragma unroll
    for (int i = 0; i < 4; ++i) {        // B tile: 128 rows x 64 k
      int t = i * 256 + tid;
      int r = t >> 3, c = (t & 7) ^ (r & 7);
      gload16(Bt + (size_t)(col0 + r) * K + k0 + c * 8, (char*)b_s + t * 16);
    }
    __syncthreads();
    #pragma unroll
    for (int kk = 0; kk < 2; ++kk) {
      bf16x8 af[2], bfr[4];
      #pragma unroll
      for (int mi = 0; mi < 2; ++mi) {
        int r = wr * 32 + mi * 16 + lr;
        int c = (lg + 4 * kk) ^ (r & 7);
        af[mi] = *(const bf16x8*)&a_s[r * 64 + c * 8];
      }
      #pragma unroll
      for (int ni = 0; ni < 4; ++ni) {
        int r = wc * 64 + ni * 16 + lr;
        int c = (lg + 4 * kk) ^ (r & 7);
        bfr[ni] = *(const bf16x8*)&b_s[r * 64 + c * 8];
      }
      #pragma unroll
      for (int mi = 0; mi < 2; ++mi)
        #pragma unroll
        for (int ni = 0; ni < 4; ++ni)
          acc[mi][ni] = MFMA_B16(af[mi], bfr[ni], acc[mi][ni]);
    }
  }
  #pragma unroll
  for (int ni = 0; ni < 4; ++ni) {
    int gc = col0 + wc * 64 + ni * 16 + lr;
    float bv = bias ? bias[gc] : 0.f;
    #pragma unroll
    for (int mi = 0; mi < 2; ++mi) {
      #pragma unroll
      for (int r = 0; r < 4; ++r) {
        int gr = row0 + wr * 32 + mi * 16 + lg * 4 + r;
        float vv = acc[mi][ni][r] + bv;
        if (RELU) vv = fmaxf(vv, 0.f);
        size_t off = (size_t)gr * N + gc;
        if (OUT_BF16)
          (((__hip_bfloat16*)Cout) + (size_t)blockIdx.z * zsC)[off] = __float2bfloat16(vv);
        else
          (((float*)Cout) + (size_t)blockIdx.z * zsC)[off] = vv;
      }
    }
  }
}

// ---- MFMA flash attention (V from pre-transposed vT[b][d][j]) ----
// grid B*H*(S/64), 256 thr = 4 waves, wave owns 16 q-rows.
__global__ __launch_bounds__(256) void attn_mfma(
    const __hip_bfloat16* __restrict__ qg, const __hip_bfloat16* __restrict__ kg,
    const __hip_bfloat16* __restrict__ vT, const float* __restrict__ maskadd,
    __hip_bfloat16* __restrict__ ctx) {
  __shared__ __hip_bfloat16 k_s[64 * 64];    // [j][64d], 16B-chunk XOR swizzle
  __shared__ __hip_bfloat16 vt_s[64 * 64];   // [d][64j], 16B-chunk XOR swizzle
  const int tid = threadIdx.x;
  const int l = tid & 63, w = tid >> 6;
  const int lr = l & 15, lg = l >> 4;
  int bid = blockIdx.x;
  int it = bid & 31, hh = (bid >> 5) & 7, b = bid >> 8;
  const float inv_scale = 0.044194173824159216f;   // 1/sqrt(512) per reference

  int qrow = it * 64 + w * 16 + lr;
  const __hip_bfloat16* qp = qg + (size_t)(b * S_ + qrow) * D_ + hh * 64 + lg * 8;
  bf16x8 qf0 = *(const bf16x8*)qp;
  bf16x8 qf1 = *(const bf16x8*)(qp + 32);

  float m_i = -3e38f, l_i = 0.f;
  f32x4 oacc[4];
  #pragma unroll
  for (int d = 0; d < 4; ++d) oacc[d] = (f32x4){0.f, 0.f, 0.f, 0.f};

  const __hip_bfloat16* kb0 = kg + (size_t)b * S_ * D_ + hh * 64;
  const __hip_bfloat16* vb0 = vT + ((size_t)b * D_ + hh * 64) * S_;
  const float* mab = maskadd + b * S_;

  for (int j0 = 0; j0 < S_; j0 += 64) {
    __syncthreads();
    #pragma unroll
    for (int i = 0; i < 2; ++i) {
      int t = i * 256 + tid;
      int r = t >> 3, c = (t & 7) ^ (r & 7);
      gload16(kb0 + (size_t)(j0 + r) * D_ + c * 8, (char*)k_s + t * 16);
      gload16(vb0 + (size_t)r * S_ + j0 + c * 8, (char*)vt_s + t * 16);
    }
    __syncthreads();

    // swapped QK^T: lane holds 16 j-scores for q-row lr
    float sc[16];
    float mx = -3e38f;
    #pragma unroll
    for (int jA = 0; jA < 4; ++jA) {
      int row = jA * 16 + lr;
      int c0 = lg ^ (row & 7);
      int c1 = (lg + 4) ^ (row & 7);
      bf16x8 ka0 = *(const bf16x8*)&k_s[row * 64 + c0 * 8];
      bf16x8 ka1 = *(const bf16x8*)&k_s[row * 64 + c1 * 8];
      f32x4 z = (f32x4){0.f, 0.f, 0.f, 0.f};
      z = MFMA_B16(ka0, qf0, z);
      z = MFMA_B16(ka1, qf1, z);
      const f32x4 ma = *(const f32x4*)&mab[j0 + jA * 16 + lg * 4];
      #pragma unroll
      for (int r = 0; r < 4; ++r) {
        float s = (z[r] + ma[r]) * inv_scale;
        sc[jA * 4 + r] = s;
        mx = fmaxf(mx, s);
      }
    }
    mx = fmaxf(mx, __shfl_xor(mx, 16));
    mx = fmaxf(mx, __shfl_xor(mx, 32));
    float mnew = fmaxf(m_i, mx);
    float corr = __expf(m_i - mnew);
    float ps = 0.f;
    #pragma unroll
    for (int i = 0; i < 16; ++i) {
      float p = __expf(sc[i] - mnew);
      sc[i] = p;
      ps += p;
    }
    ps += __shfl_xor(ps, 16);
    ps += __shfl_xor(ps, 32);
    l_i = l_i * corr + ps;
    m_i = mnew;

    // P fragments: A-operand k-slot (lg,e) <-> j_local = (e>>2)*16 + lg*4 + (e&3)
    bf16x8 pa0, pa1;
    #pragma unroll
    for (int e = 0; e < 8; ++e) {
      pa0[e] = f2bf(sc[e]);
      pa1[e] = f2bf(sc[8 + e]);
    }
    float cf[4];
    #pragma unroll
    for (int r = 0; r < 4; ++r) cf[r] = __shfl(corr, lg * 4 + r);
    #pragma unroll
    for (int df = 0; df < 4; ++df)
      #pragma unroll
      for (int r = 0; r < 4; ++r) oacc[df][r] *= cf[r];

    // PV: B-frag element e needs vT[d = df*16+lr][j0 + j_local(k)]
    #pragma unroll
    for (int df = 0; df < 4; ++df) {
      int row = df * 16 + lr;
      u32x2 rv[4];
      #pragma unroll
      for (int q16 = 0; q16 < 4; ++q16) {
        int jc = q16 * 2 + (lg >> 1);
        int off = row * 128 + ((jc ^ (row & 7)) * 16) + (lg & 1) * 8;
        rv[q16] = *(const u32x2*)((const char*)vt_s + off);
      }
      u32x4 b0, b1;
      b0.x = rv[0].x; b0.y = rv[0].y; b0.z = rv[1].x; b0.w = rv[1].y;
      b1.x = rv[2].x; b1.y = rv[2].y; b1.z = rv[3].x; b1.w = rv[3].y;
      oacc[df] = MFMA_B16(pa0, __builtin_bit_cast(bf16x8, b0), oacc[df]);
      oacc[df] = MFMA_B16(pa1, __builtin_bit_cast(bf16x8, b1), oacc[df]);
    }
  }

  float li[4];
  #pragma unroll
  for (int r = 0; r < 4; ++r) li[r] = __shfl(l_i, lg * 4 + r);
  #pragma unroll
  for (int df = 0; df < 4; ++df) {
    #pragma unroll
    for (int r = 0; r < 4; ++r) {
      int gr = it * 64 + w * 16 + lg * 4 + r;
      ctx[(size_t)(b * S_ + gr) * D_ + hh * 64 + df * 16 + lr] =
          __float2bfloat16(oacc[df][r] / li[r]);
    }
  }
}

// ---- add + LayerNorm. In-place safe for outf==a (loads precede barrier 1,
// stores follow barrier 2); NO __restrict__ on aliasable pointers.
__global__ __launch_bounds__(256) void ln_add_kernel(
    const float* a, const float* bsrc,
    const float* g, const float* be,
    float* outf, __hip_bfloat16* outb) {
  int row = blockIdx.x;
  int tid = threadIdx.x;
  size_t base = (size_t)row * D_;
  float s0 = a[base + tid] + bsrc[base + tid];
  float s1 = a[base + 256 + tid] + bsrc[base + 256 + tid];
  float sum = s0 + s1;
  #pragma unroll
  for (int o = 1; o < 64; o <<= 1) sum += __shfl_xor(sum, o);
  __shared__ float red[4], red2[4];
  int w = tid >> 6, lane = tid & 63;
  if (lane == 0) red[w] = sum;
  __syncthreads();
  float mu = (red[0] + red[1] + red[2] + red[3]) * (1.f / D_);
  float d0 = s0 - mu, d1 = s1 - mu;
  float vs = d0 * d0 + d1 * d1;
  #pragma unroll
  for (int o = 1; o < 64; o <<= 1) vs += __shfl_xor(vs, o);
  if (lane == 0) red2[w] = vs;
  __syncthreads();
  float var = (red2[0] + red2[1] + red2[2] + red2[3]) * (1.f / D_);
  float rstd = rsqrtf(var + 1e-5f);
  float n0 = d0 * rstd * g[tid] + be[tid];
  float n1 = d1 * rstd * g[256 + tid] + be[256 + tid];
  outf[base + tid] = n0;
  outf[base + 256 + tid] = n1;
  outb[base + tid] = __float2bfloat16(n0);
  outb[base + 256 + tid] = __float2bfloat16(n1);
}

extern "C" void kernel_launch(void* const* d_in, const int* in_sizes, int n_in,
                              void* d_out, int out_size, void* d_ws, size_t ws_size,
                              hipStream_t stream) {
  (void)in_sizes; (void)n_in; (void)out_size; (void)ws_size;
  const int*   x      = (const int*)  d_in[0];
  const int*   mask   = (const int*)  d_in[1];
  const float* word_e = (const float*)d_in[2];
  const float* pos_e  = (const float*)d_in[3];
  const float* Wv     = (const float*)d_in[4];
  const float* Wk     = (const float*)d_in[5];
  const float* Wq     = (const float*)d_in[6];
  const float* Wo     = (const float*)d_in[7];
  const float* bo     = (const float*)d_in[8];
  const float* W1     = (const float*)d_in[9];
  const float* b1     = (const float*)d_in[10];
  const float* W2     = (const float*)d_in[11];
  const float* b2     = (const float*)d_in[12];
  const float* gamma  = (const float*)d_in[13];
  const float* beta   = (const float*)d_in[14];
  float* out = (float*)d_out;

  // ---- workspace layout (48.25 MB total; round-1 proved >=50.3 MB exists) ----
  char* p = (char*)d_ws;
  __hip_bfloat16* wt   = (__hip_bfloat16*)p; p += (4 * DD_ + 2 * DF_) * 2; // 6.29 MB
  float* maf = (float*)p; p += (size_t)BS_ * 4;                            // 16 KB
  float* h   = (float*)p; p += BSD_ * 4;                                   // 8.39 MB
  float* h1  = (float*)p; p += BSD_ * 4;                                   // 8.39 MB
  __hip_bfloat16* hbf  = (__hip_bfloat16*)p; p += BSD_ * 2;                // 4.19 MB
  __hip_bfloat16* h1bf = (__hip_bfloat16*)p; p += BSD_ * 2;                // 4.19 MB
  __hip_bfloat16* qkv  = (__hip_bfloat16*)p; p += 4 * BSD_ * 2;            // 16.78 MB
  __hip_bfloat16* qb   = qkv;
  __hip_bfloat16* kb   = qkv + BSD_;
  __hip_bfloat16* vb   = qkv + 2 * BSD_;
  __hip_bfloat16* ctxb = qkv + 3 * BSD_;
  __hip_bfloat16* ff1  = qkv;          // overlays q,k,v,ctx (dead by then)
  __hip_bfloat16* vTb  = h1bf;         // vT lifetime [post-QKV, attn] disjoint
                                       // from h1bf lifetime [ln_add1, W1-GEMM]

  dim3 blk(256);
  maskadd_kernel<<<BS_ / 256, blk, 0, stream>>>(mask, maf);
  embed_kernel<<<(int)(BSD_ / 256), blk, 0, stream>>>(x, word_e, pos_e, h, hbf);

  for (int l = 0; l < L_; ++l) {
    const float* bo_l = bo + (size_t)l * D_;
    const float* b1_l = b1 + (size_t)l * DFF_;
    const float* b2_l = b2 + (size_t)l * D_;
    const float* g_l  = gamma + (size_t)l * D_;
    const float* be_l = beta  + (size_t)l * D_;

    wtrans_layer<<<3072, blk, 0, stream>>>(
        Wq + l * DD_, Wk + l * DD_, Wv + l * DD_, Wo + l * DD_,
        W1 + l * DF_, W2 + l * DF_, wt);

    // QKV fused: z in {0,1,2}
    gemm_bf16<1, 0><<<dim3(D_ / 128, BS_ / 64, 3), blk, 0, stream>>>(
        hbf, wt, nullptr, qb, D_, D_, DD_, BSD_);

    vtrans<<<dim3(S_ / 32, D_ / 32, B_), blk, 0, stream>>>(vb, vTb);

    attn_mfma<<<dim3(B_ * H_ * (S_ / 64)), blk, 0, stream>>>(qb, kb, vTb, maf, ctxb);

    gemm_bf16<0, 0><<<dim3(D_ / 128, BS_ / 64, 1), blk, 0, stream>>>(
        ctxb, wt + 3 * DD_, bo_l, h1, D_, D_, 0, 0);
    ln_add_kernel<<<BS_, blk, 0, stream>>>(h1, h, g_l, be_l, h1, h1bf); // in-place

    gemm_bf16<1, 1><<<dim3(DFF_ / 128, BS_ / 64, 1), blk, 0, stream>>>(
        h1bf, wt + 4 * DD_, b1_l, ff1, DFF_, D_, 0, 0);
    gemm_bf16<0, 0><<<dim3(D_ / 128, BS_ / 64, 1), blk, 0, stream>>>(
        ff1, wt + 4 * DD_ + DF_, b2_l, h, D_, DFF_, 0, 0);
    ln_add_kernel<<<BS_, blk, 0, stream>>>(h, h1, g_l, be_l,
                                           (l == L_ - 1) ? out : h, hbf); // in-place
  }
}